// Round 3
// baseline (493.278 us; speedup 1.0000x reference)
//
#include <hip/hip_runtime.h>

// X [B, N, D] fp32, mask [B, N] int (1 = masked OUT), W [D], b [D].
// B=64, N=8192, D=128. REPLACE = 0.0 -> masked rows output b[d].
#define B_ 64
#define N_ 8192
#define D_ 128
#define D4 (D_ / 4)            // 32 float4 per row
#define NCHUNKS 16
#define CHUNK (N_ / NCHUNKS)   // 512 rows per reduce block

// Native vector type: __builtin_nontemporal_store requires it (HIP float4 class is rejected).
typedef float v4f __attribute__((ext_vector_type(4)));

// Workspace layout (floats) — every slot fully written before read, no init needed:
//  [WS_SUMP,  +B*NCHUNKS*D)   per-(b,chunk) partial sums          (131072)
//  [WS_SQP,   +B*NCHUNKS*D)   per-(b,chunk) partial sum-of-squares(131072)
//  [WS_CNTP,  +B*NCHUNKS)     per-(b,chunk) valid-row counts      (1024)
//  [WS_SCALE, +B*D)           W*rsqrt(var)                        (8192)
//  [WS_SHIFT, +B*D)           b - mean*scale                      (8192)
#define WS_SUMP  0
#define WS_SQP   (B_ * NCHUNKS * D_)
#define WS_CNTP  (2 * B_ * NCHUNKS * D_)
#define WS_SCALE (2 * B_ * NCHUNKS * D_ + B_ * NCHUNKS)
#define WS_SHIFT (WS_SCALE + B_ * D_)

__global__ __launch_bounds__(256) void reduce_kernel(
        const float* __restrict__ X, const int* __restrict__ mask,
        float* __restrict__ ws) {
    const int b   = blockIdx.x;
    const int cy  = blockIdx.y;
    const int tid = threadIdx.x;
    const int q   = tid & 31;   // float4 column within row
    const int sub = tid >> 5;   // 0..7 row phase
    const int n0  = cy * CHUNK;

    const v4f* __restrict__ Xr = (const v4f*)(X + (size_t)b * N_ * D_);
    const int* __restrict__ mr = mask + b * N_;

    v4f s  = (v4f)(0.f);
    v4f ss = (v4f)(0.f);
    float cnt = 0.f;

    // Branchless: always load, scale by validity. Unroll for memory-level parallelism.
    #pragma unroll 4
    for (int k = 0; k < CHUNK / 8; ++k) {
        const int n = n0 + sub + 8 * k;
        const float v = (mr[n] == 0) ? 1.0f : 0.0f;
        v4f x = Xr[(size_t)n * D4 + q];
        x *= v;                 // masked rows -> 0
        s += x;
        ss += x * x;
        cnt += v;               // identical across the 32 q-lanes
    }

    __shared__ v4f sh_s[8][32];
    __shared__ v4f sh_ss[8][32];
    __shared__ float sh_c[8];
    sh_s[sub][q]  = s;
    sh_ss[sub][q] = ss;
    if (q == 0) sh_c[sub] = cnt;
    __syncthreads();

    if (sub == 0) {
        v4f ts = s, tss = ss;
        for (int k = 1; k < 8; ++k) {
            ts  += sh_s[k][q];
            tss += sh_ss[k][q];
        }
        v4f* __restrict__ sump = (v4f*)(ws + WS_SUMP);
        v4f* __restrict__ sqp  = (v4f*)(ws + WS_SQP);
        const int slot = (b * NCHUNKS + cy) * D4 + q;
        sump[slot] = ts;
        sqp[slot]  = tss;
    }
    if (tid == 0) {
        float c = 0.f;
        for (int k = 0; k < 8; ++k) c += sh_c[k];
        ws[WS_CNTP + b * NCHUNKS + cy] = c;
    }
}

__global__ __launch_bounds__(256) void finalize_kernel(
        const float* __restrict__ W, const float* __restrict__ bias,
        float* __restrict__ ws) {
    const float* __restrict__ sump = ws + WS_SUMP;
    const float* __restrict__ sqp  = ws + WS_SQP;
    const float* __restrict__ cntp = ws + WS_CNTP;
    float* __restrict__ scale = ws + WS_SCALE;
    float* __restrict__ shift = ws + WS_SHIFT;

    const int i = blockIdx.x * blockDim.x + threadIdx.x;   // 0 .. B*D
    if (i >= B_ * D_) return;
    const int b = i >> 7;          // / D_
    const int d = i & (D_ - 1);

    float c = 0.f, s = 0.f, sq = 0.f;
    #pragma unroll
    for (int cy = 0; cy < NCHUNKS; ++cy) {
        c  += cntp[b * NCHUNKS + cy];
        s  += sump[(b * NCHUNKS + cy) * D_ + d];
        sq += sqp [(b * NCHUNKS + cy) * D_ + d];
    }
    const float mean = s / c;
    const float var  = (sq - s * mean) / (c - 1.0f);   // unbiased
    const float sc   = W[d] * rsqrtf(var);
    scale[i] = sc;
    shift[i] = bias[d] - mean * sc;
}

__global__ __launch_bounds__(256) void normalize_kernel(
        const float* __restrict__ X, const int* __restrict__ mask,
        const float* __restrict__ ws, const float* __restrict__ bias,
        float* __restrict__ out) {
    const v4f* __restrict__ X4 = (const v4f*)X;
    v4f* __restrict__ O4 = (v4f*)out;
    const v4f* __restrict__ S4 = (const v4f*)(ws + WS_SCALE);
    const v4f* __restrict__ H4 = (const v4f*)(ws + WS_SHIFT);
    const v4f* __restrict__ B4 = (const v4f*)bias;

    const long long total = (long long)B_ * N_ * D4;   // float4 elements
    long long i = (long long)blockIdx.x * blockDim.x + threadIdx.x;
    const long long stride = (long long)gridDim.x * blockDim.x;

    for (; i < total; i += stride) {
        const int row = (int)(i >> 5);        // / D4
        const int c   = (int)(i & 31);
        const int b   = row >> 13;            // / N_
        const int m   = mask[row];
        const v4f x  = X4[i];                 // unconditional: no branch in the load path
        const v4f sc = S4[b * D4 + c];
        const v4f sh = H4[b * D4 + c];
        const v4f bb = B4[c];
        const v4f norm = x * sc + sh;
        v4f o;
        o.x = m ? bb.x : norm.x;
        o.y = m ? bb.y : norm.y;
        o.z = m ? bb.z : norm.z;
        o.w = m ? bb.w : norm.w;
        // Nontemporal: don't let the 256 MiB output evict X from the LLC.
        __builtin_nontemporal_store(o, &O4[i]);
    }
}

extern "C" void kernel_launch(void* const* d_in, const int* in_sizes, int n_in,
                              void* d_out, int out_size, void* d_ws, size_t ws_size,
                              hipStream_t stream) {
    const float* X    = (const float*)d_in[0];
    const int*   mask = (const int*)d_in[1];
    const float* W    = (const float*)d_in[2];
    const float* bias = (const float*)d_in[3];
    float* out = (float*)d_out;
    float* ws  = (float*)d_ws;

    // 1) per-(batch, chunk) partial sums / sumsq / counts (deterministic, no atomics)
    reduce_kernel<<<dim3(B_, NCHUNKS), 256, 0, stream>>>(X, mask, ws);

    // 2) mean/var -> scale/shift
    finalize_kernel<<<(B_ * D_ + 255) / 256, 256, 0, stream>>>(W, bias, ws);

    // 3) elementwise normalize + affine + mask-replace (branchless select)
    normalize_kernel<<<4096, 256, 0, stream>>>(X, mask, ws, bias, out);
}

// Round 4
// 434.906 us; speedup vs baseline: 1.1342x; 1.1342x over previous
//
#include <hip/hip_runtime.h>

// X [B, N, D] fp32, mask [B, N] int (1 = masked OUT), W [D], b [D].
// B=64, N=8192, D=128. REPLACE = 0.0 -> masked rows output b[d].
#define B_ 64
#define N_ 8192
#define D_ 128
#define D4 (D_ / 4)            // 32 float4 per row
#define NCHUNKS 32
#define CHUNK (N_ / NCHUNKS)   // 256 rows per reduce block

// Native vector type: __builtin_nontemporal_store requires it (HIP float4 class is rejected).
typedef float v4f __attribute__((ext_vector_type(4)));

// Workspace layout (floats) — every slot fully written before read, no init needed:
//  [WS_SUMP,  +B*NCHUNKS*D)   per-(b,chunk) partial sums
//  [WS_SQP,   +B*NCHUNKS*D)   per-(b,chunk) partial sum-of-squares
//  [WS_CNTP,  +B*NCHUNKS)     per-(b,chunk) valid-row counts
//  [WS_SCALE, +B*D)           W*rsqrt(var)
//  [WS_SHIFT, +B*D)           b - mean*scale
#define WS_SUMP  0
#define WS_SQP   (B_ * NCHUNKS * D_)
#define WS_CNTP  (2 * B_ * NCHUNKS * D_)
#define WS_SCALE (2 * B_ * NCHUNKS * D_ + B_ * NCHUNKS)
#define WS_SHIFT (WS_SCALE + B_ * D_)

__global__ __launch_bounds__(256) void reduce_kernel(
        const float* __restrict__ X, const int* __restrict__ mask,
        float* __restrict__ ws) {
    const int b   = blockIdx.x;
    const int cy  = blockIdx.y;
    const int tid = threadIdx.x;
    const int q   = tid & 31;   // float4 column within row
    const int sub = tid >> 5;   // 0..7 row phase
    const int n0  = cy * CHUNK;

    // Preload this chunk's mask into LDS as 0/1 floats: removes the global
    // mask load -> X load dependency from the hot loop entirely.
    __shared__ float valid[CHUNK];
    valid[tid] = (mask[b * N_ + n0 + tid] == 0) ? 1.0f : 0.0f;
    __syncthreads();

    const v4f* __restrict__ Xr =
        (const v4f*)(X + (size_t)b * N_ * D_) + (size_t)n0 * D4 + q;

    v4f s  = (v4f)(0.f);
    v4f ss = (v4f)(0.f);
    float cnt = 0.f;

    // Branch-skip masked rows: a masked row is 512 contiguous bytes that are
    // then never fetched from HBM (~50% fetch saved).
    #pragma unroll
    for (int k = 0; k < CHUNK / 8; ++k) {      // 32 iterations
        const int n = sub + 8 * k;
        const float v = valid[n];              // LDS broadcast across q lanes
        cnt += v;
        if (v != 0.0f) {
            const v4f x = Xr[(size_t)n * D4];
            s += x;
            ss += x * x;
        }
    }

    __shared__ v4f sh_s[8][32];
    __shared__ v4f sh_ss[8][32];
    __shared__ float sh_c[8];
    sh_s[sub][q]  = s;
    sh_ss[sub][q] = ss;
    if (q == 0) sh_c[sub] = cnt;
    __syncthreads();

    if (sub == 0) {
        v4f ts = s, tss = ss;
        #pragma unroll
        for (int k = 1; k < 8; ++k) {
            ts  += sh_s[k][q];
            tss += sh_ss[k][q];
        }
        v4f* __restrict__ sump = (v4f*)(ws + WS_SUMP);
        v4f* __restrict__ sqp  = (v4f*)(ws + WS_SQP);
        const int slot = (b * NCHUNKS + cy) * D4 + q;
        sump[slot] = ts;
        sqp[slot]  = tss;
    }
    if (tid == 0) {
        float c = 0.f;
        #pragma unroll
        for (int k = 0; k < 8; ++k) c += sh_c[k];
        ws[WS_CNTP + b * NCHUNKS + cy] = c;
    }
}

__global__ __launch_bounds__(256) void finalize_kernel(
        const float* __restrict__ W, const float* __restrict__ bias,
        float* __restrict__ ws) {
    const float* __restrict__ sump = ws + WS_SUMP;
    const float* __restrict__ sqp  = ws + WS_SQP;
    const float* __restrict__ cntp = ws + WS_CNTP;
    float* __restrict__ scale = ws + WS_SCALE;
    float* __restrict__ shift = ws + WS_SHIFT;

    const int i = blockIdx.x * blockDim.x + threadIdx.x;   // 0 .. B*D
    if (i >= B_ * D_) return;
    const int b = i >> 7;          // / D_
    const int d = i & (D_ - 1);

    float c = 0.f, s = 0.f, sq = 0.f;
    #pragma unroll
    for (int cy = 0; cy < NCHUNKS; ++cy) {
        c  += cntp[b * NCHUNKS + cy];
        s  += sump[(b * NCHUNKS + cy) * D_ + d];
        sq += sqp [(b * NCHUNKS + cy) * D_ + d];
    }
    const float mean = s / c;
    const float var  = (sq - s * mean) / (c - 1.0f);   // unbiased
    const float sc   = W[d] * rsqrtf(var);
    scale[i] = sc;
    shift[i] = bias[d] - mean * sc;
}

__global__ __launch_bounds__(256) void normalize_kernel(
        const float* __restrict__ X, const int* __restrict__ mask,
        const float* __restrict__ ws, const float* __restrict__ bias,
        float* __restrict__ out) {
    const v4f* __restrict__ X4 = (const v4f*)X;
    v4f* __restrict__ O4 = (v4f*)out;
    const v4f* __restrict__ S4 = (const v4f*)(ws + WS_SCALE);
    const v4f* __restrict__ H4 = (const v4f*)(ws + WS_SHIFT);
    const v4f* __restrict__ B4 = (const v4f*)bias;

    // One thread per float4: no loop, maximal memory-level parallelism.
    const int i   = blockIdx.x * 256 + threadIdx.x;   // float4 index, < 2^24
    const int row = i >> 5;          // / D4
    const int c   = i & 31;
    const int b   = row >> 13;       // / N_

    if (mask[row] != 0) {
        // Masked row: output b[d]; X never fetched (saves ~50% of the re-read).
        __builtin_nontemporal_store(B4[c], &O4[i]);
    } else {
        const v4f x  = X4[i];
        const v4f sc = S4[(b << 5) + c];
        const v4f sh = H4[(b << 5) + c];
        __builtin_nontemporal_store(x * sc + sh, &O4[i]);
    }
}

extern "C" void kernel_launch(void* const* d_in, const int* in_sizes, int n_in,
                              void* d_out, int out_size, void* d_ws, size_t ws_size,
                              hipStream_t stream) {
    const float* X    = (const float*)d_in[0];
    const int*   mask = (const int*)d_in[1];
    const float* W    = (const float*)d_in[2];
    const float* bias = (const float*)d_in[3];
    float* out = (float*)d_out;
    float* ws  = (float*)d_ws;

    // 1) per-(batch, chunk) partial sums / sumsq / counts (no atomics, mask in LDS)
    reduce_kernel<<<dim3(B_, NCHUNKS), 256, 0, stream>>>(X, mask, ws);

    // 2) mean/var -> scale/shift
    finalize_kernel<<<(B_ * D_ + 255) / 256, 256, 0, stream>>>(W, bias, ws);

    // 3) elementwise normalize + affine + mask-replace (branch skips X fetch on masked rows)
    normalize_kernel<<<(B_ * N_ * D4) / 256, 256, 0, stream>>>(X, mask, ws, bias, out);
}